// Round 12
// baseline (293.268 us; speedup 1.0000x reference)
//
#include <hip/hip_runtime.h>
#include <hip/hip_fp16.h>

#define NN 100000     // num nodes
#define NE 1600000    // num edges
#define NEL 200000    // link-pred edges
#define TM 64         // nodes per block in k_hw1

// Bucketed CSR build: bucket = dst >> 9. R26: deterministic block-private
// partition regions part[block][bucket][CAPR] — no gcur, no global atomics,
// no memset node (7 -> 6 graph nodes; ~14 us/node gap measured R8/R11).
// Structural alternatives ALL measured worse: fused part+build (+19 us, R9),
// atomic-append scatter (17x write amp, +151 us, R10), bucket-direct gather
// (TLP collapse, 4.8x, R7), megakernel (4.4x, R6). Do not revisit.
#define NBUCK 196     // ceil(NN/512)
#define CAPB  10240   // per-bucket total capacity (mean 8163, sigma ~90)
#define CAPR  96      // per-(block,bucket) run capacity (mean 41.8, 8.4 sigma)
#define TPE   8192    // edges per k_part block (196 blocks)

typedef short s16x8 __attribute__((ext_vector_type(8)));
typedef float f32x4 __attribute__((ext_vector_type(4)));

__device__ __forceinline__ unsigned short bf16hi(float v) {
    unsigned u = __float_as_uint(v);
    return (unsigned short)((u + 0x7FFFu + ((u >> 16) & 1u)) >> 16);
}
__device__ __forceinline__ float bf16tof(unsigned short b) {
    return __uint_as_float(((unsigned)b) << 16);
}

// ---------------- CSR pass A: deterministic partition ----------------------
// One pass over the edge tile: LDS rank counter per bucket -> block-private
// run part[blk][bucket][CAPR]; run lengths written to rcnt AFTER the scatter
// (rank counters ARE the histogram — the old separate hist pass is deleted).
__global__ __launch_bounds__(256) void k_part(const int* __restrict__ src,
                                              const int* __restrict__ dst,
                                              int* __restrict__ part,
                                              int* __restrict__ rcnt) {
    __shared__ int rk[NBUCK];
    int tid = threadIdx.x;
    int blk = blockIdx.x;
    for (int i = tid; i < NBUCK; i += 256) rk[i] = 0;
    __syncthreads();
    int e0 = blk * TPE;
    int e1 = min(e0 + TPE, NE);
    int rbase = blk * NBUCK;
    for (int e = e0 + tid; e < e1; e += 256) {
        int d = dst[e];
        int s = src[e];
        int b = d >> 9;
        int r = atomicAdd(&rk[b], 1);
        if (r < CAPR)                           // 8.4-sigma guard
            part[(rbase + b) * CAPR + r] = ((d & 511) << 17) | s;  // src < 2^17
    }
    __syncthreads();
    for (int i = tid; i < NBUCK; i += 256)
        rcnt[rbase + i] = min(rk[i], CAPR);
}

// ---------------- CSR pass B: per-bucket LDS sort (runs consumed wave/run) -
// Bucket totals from rcnt column sums (coalesced across threads); inline
// 196-bucket prefix (existing Hillis-Steele). Runs are ~42 elems: wave w
// takes runs w, w+4, ...; inner o-loop covers the rare cj > 64.
// off[] end convention: row d = [off[d-1], off[d]), off[-1] = 0.
__global__ __launch_bounds__(256) void k_build(const int* __restrict__ rcnt,
                                               const int* __restrict__ part,
                                               int* __restrict__ csr,
                                               int* __restrict__ off,
                                               float* __restrict__ dinv) {
    __shared__ int tot[256];
    __shared__ int rcl[NBUCK];
    __shared__ int hist[512];
    __shared__ int loff[512];
    __shared__ int ssum[256];
    __shared__ int csrbuf[CAPB];
    int b = blockIdx.x;
    int tid = threadIdx.x;
    // bucket totals: thread k sums column k of rcnt (coalesced per row j)
    int sum = 0;
    if (tid < NBUCK)
        for (int j = 0; j < NBUCK; ++j) sum += rcnt[j * NBUCK + tid];
    tot[tid] = (tid < NBUCK) ? sum : 0;
    for (int j = tid; j < NBUCK; j += 256) rcl[j] = rcnt[j * NBUCK + b];
    __syncthreads();
    int cnt = tot[b];                          // own total, pre-prefix
    for (int st = 1; st < 256; st <<= 1) {     // inclusive prefix over tot
        int tmp = (tid >= st) ? tot[tid - st] : 0;
        __syncthreads();
        tot[tid] += tmp;
        __syncthreads();
    }
    int obase = tot[b] - cnt;                  // exclusive prefix
    hist[tid] = 0; hist[tid + 256] = 0;
    __syncthreads();
    int w = tid >> 6, lane = tid & 63;
    for (int j = w; j < NBUCK; j += 4) {       // histogram pass, wave per run
        int cj = rcl[j];
        int pb = (j * NBUCK + b) * CAPR;
        for (int o = 0; o < cj; o += 64)
            if (o + lane < cj) {
                int rec = part[pb + o + lane];
                atomicAdd(&hist[rec >> 17], 1);
            }
    }
    __syncthreads();
    int a0 = hist[2 * tid], a1 = hist[2 * tid + 1];
    int pairs = a0 + a1;
    ssum[tid] = pairs;
    __syncthreads();
    for (int st = 1; st < 256; st <<= 1) {
        int tmp = (tid >= st) ? ssum[tid - st] : 0;
        __syncthreads();
        ssum[tid] += tmp;
        __syncthreads();
    }
    int pexcl = ssum[tid] - pairs;
    loff[2 * tid] = pexcl;
    loff[2 * tid + 1] = pexcl + a0;
    __syncthreads();
    for (int i = tid; i < 512; i += 256) {
        int d = b * 512 + i;
        if (d < NN) {
            int c = hist[i];
            off[d] = obase + loff[i] + c;            // end of row d
            dinv[d] = rsqrtf((float)(c + 1));        // +1 self-loop
        }
    }
    hist[tid] = 0; hist[tid + 256] = 0;              // reuse as rank counters
    __syncthreads();
    for (int j = w; j < NBUCK; j += 4) {       // rank-scatter pass
        int cj = rcl[j];
        int pb = (j * NBUCK + b) * CAPR;
        for (int o = 0; o < cj; o += 64)
            if (o + lane < cj) {
                int rec = part[pb + o + lane];
                int dl = rec >> 17;
                int r = atomicAdd(&hist[dl], 1);
                csrbuf[loff[dl] + r] = rec & 0x1FFFF;
            }
    }
    __syncthreads();
    for (int i = tid; i < cnt; i += 256)             // coalesced flush
        csr[obase + i] = csrbuf[i];
}

// ---------------- hw1' = dinv * ([x|pos] @ W1)  (80 -> 64), MFMA bf16-split
// bf16 hi/lo split (Ahi*Bhi + Ahi*Blo + Alo*Bhi) -> fp32-class accuracy.
#define HW1_K 104
__global__ __launch_bounds__(256) void k_hw1(const float* __restrict__ x,
                                             const float* __restrict__ pos,
                                             const float* __restrict__ W1,
                                             const float* __restrict__ dinv,
                                             __half* __restrict__ hw1) {
    __shared__ unsigned short ahi[64 * HW1_K];
    __shared__ unsigned short alo[64 * HW1_K];
    __shared__ unsigned short bhi[64 * HW1_K];
    __shared__ unsigned short blo[64 * HW1_K];
    __shared__ float sdin[64];
    int tid = threadIdx.x;
    int nb = blockIdx.x * 64;
    for (int i = tid; i < 64 * 24; i += 256) {
        int r = i / 24, c = i - r * 24;
        ahi[r * HW1_K + 80 + c] = 0; alo[r * HW1_K + 80 + c] = 0;
        bhi[r * HW1_K + 80 + c] = 0; blo[r * HW1_K + 80 + c] = 0;
    }
    for (int i = tid; i < 64 * 64; i += 256) {
        int r = i >> 6, c = i & 63;
        int g = nb + r;
        float v = (g < NN) ? x[g * 64 + c] : 0.0f;
        unsigned short h = bf16hi(v);
        ahi[r * HW1_K + c] = h;
        alo[r * HW1_K + c] = bf16hi(v - bf16tof(h));
    }
    for (int i = tid; i < 64 * 16; i += 256) {
        int r = i >> 4, c = i & 15;
        int g = nb + r;
        float v = (g < NN) ? pos[g * 16 + c] : 0.0f;
        unsigned short h = bf16hi(v);
        ahi[r * HW1_K + 64 + c] = h;
        alo[r * HW1_K + 64 + c] = bf16hi(v - bf16tof(h));
    }
    for (int i = tid; i < 80 * 64; i += 256) {
        int k = i >> 6, c = i & 63;
        float v = W1[i];
        unsigned short h = bf16hi(v);
        bhi[c * HW1_K + k] = h;
        blo[c * HW1_K + k] = bf16hi(v - bf16tof(h));
    }
    for (int i = tid; i < 64; i += 256) {
        int g = nb + i;
        sdin[i] = (g < NN) ? dinv[g] : 0.0f;
    }
    __syncthreads();
    int wave = tid >> 6, lane = tid & 63;
    int frow = lane & 15, fq = lane >> 4;
    int r0 = wave * 16;                        // wave owns 16 rows x 64 cols
    int aoff = (r0 + frow) * HW1_K + fq * 8;
    s16x8 ah0 = *(s16x8*)&ahi[aoff];
    s16x8 ah1 = *(s16x8*)&ahi[aoff + 32];
    s16x8 ah2 = *(s16x8*)&ahi[aoff + 64];
    s16x8 al0 = *(s16x8*)&alo[aoff];
    s16x8 al1 = *(s16x8*)&alo[aoff + 32];
    s16x8 al2 = *(s16x8*)&alo[aoff + 64];
    f32x4 acc[4];
#pragma unroll
    for (int ct = 0; ct < 4; ++ct) {
        acc[ct] = (f32x4)(0.0f);
        int boff = (ct * 16 + frow) * HW1_K + fq * 8;
        s16x8 bh0 = *(s16x8*)&bhi[boff];
        s16x8 bh1 = *(s16x8*)&bhi[boff + 32];
        s16x8 bh2 = *(s16x8*)&bhi[boff + 64];
        s16x8 bl0 = *(s16x8*)&blo[boff];
        s16x8 bl1 = *(s16x8*)&blo[boff + 32];
        s16x8 bl2 = *(s16x8*)&blo[boff + 64];
        acc[ct] = __builtin_amdgcn_mfma_f32_16x16x32_bf16(ah0, bh0, acc[ct], 0, 0, 0);
        acc[ct] = __builtin_amdgcn_mfma_f32_16x16x32_bf16(ah1, bh1, acc[ct], 0, 0, 0);
        acc[ct] = __builtin_amdgcn_mfma_f32_16x16x32_bf16(ah2, bh2, acc[ct], 0, 0, 0);
        acc[ct] = __builtin_amdgcn_mfma_f32_16x16x32_bf16(ah0, bl0, acc[ct], 0, 0, 0);
        acc[ct] = __builtin_amdgcn_mfma_f32_16x16x32_bf16(ah1, bl1, acc[ct], 0, 0, 0);
        acc[ct] = __builtin_amdgcn_mfma_f32_16x16x32_bf16(ah2, bl2, acc[ct], 0, 0, 0);
        acc[ct] = __builtin_amdgcn_mfma_f32_16x16x32_bf16(al0, bh0, acc[ct], 0, 0, 0);
        acc[ct] = __builtin_amdgcn_mfma_f32_16x16x32_bf16(al1, bh1, acc[ct], 0, 0, 0);
        acc[ct] = __builtin_amdgcn_mfma_f32_16x16x32_bf16(al2, bh2, acc[ct], 0, 0, 0);
    }
#pragma unroll
    for (int ct = 0; ct < 4; ++ct) {
        int col = ct * 16 + frow;
#pragma unroll
        for (int i = 0; i < 4; ++i) {
            int r = r0 + fq * 4 + i;           // C/D: col=lane&15, row=(lane>>4)*4+i
            int g = nb + r;
            if (g < NN)
                hw1[g * 64 + col] = __float2half_rn(acc[ct][i] * sdin[r]);
        }
    }
}

// ---------------- layer-1 gather + FUSED hw2 row-GEMM (slim epilogue) ------
// Gather loop = proven R18 masked 16-deep (chip random-line ceiling ~30
// req/ns — do not restructure). Fused hw2 (R8, −21 us net); slim W2-direct
// epilogue (R11, −6 us). Landmines: R15 channel-slice 3.2x; R16 index
// arrays 5x; R6 mega 4.4x; R7 bucket-scatter 4.8x; R10 atomic-append 17x.
__global__ __launch_bounds__(256) void k_gather1(const int* __restrict__ off,
                                                 const int* __restrict__ csr,
                                                 const float* __restrict__ dinv,
                                                 const __half* __restrict__ hw,
                                                 const float* __restrict__ b1,
                                                 const float* __restrict__ W2,
                                                 __half* __restrict__ hw2out) {
    __shared__ float h2row[4][64];             // 1 KB, wave-private rows
    int tid = threadIdx.x;
    int lane = tid & 63;
    int wave = tid >> 6;
    int d = blockIdx.x * 4 + wave;             // grid = NN/4 exactly
    int start = (d == 0) ? 0 : off[d - 1];
    int end = off[d];
    start = __builtin_amdgcn_readfirstlane(start);   // SGPR bounds ->
    end   = __builtin_amdgcn_readfirstlane(end);     // scalar csr loads
    float dd = dinv[d];
    float hself = __half2float(hw[d * 64 + lane]);   // hoisted
    float acc0 = 0.0f, acc1 = 0.0f, acc2 = 0.0f, acc3 = 0.0f;
    for (int e = start; e < end; e += 16) {
        int rem = end - e;                     // >= 1 (SGPR)
        int s0 = csr[e];
        int s1  = (rem > 1)  ? csr[e + 1]  : s0;
        int s2  = (rem > 2)  ? csr[e + 2]  : s0;
        int s3  = (rem > 3)  ? csr[e + 3]  : s0;
        int s4  = (rem > 4)  ? csr[e + 4]  : s0;
        int s5  = (rem > 5)  ? csr[e + 5]  : s0;
        int s6  = (rem > 6)  ? csr[e + 6]  : s0;
        int s7  = (rem > 7)  ? csr[e + 7]  : s0;
        int s8  = (rem > 8)  ? csr[e + 8]  : s0;
        int s9  = (rem > 9)  ? csr[e + 9]  : s0;
        int s10 = (rem > 10) ? csr[e + 10] : s0;
        int s11 = (rem > 11) ? csr[e + 11] : s0;
        int s12 = (rem > 12) ? csr[e + 12] : s0;
        int s13 = (rem > 13) ? csr[e + 13] : s0;
        int s14 = (rem > 14) ? csr[e + 14] : s0;
        int s15 = (rem > 15) ? csr[e + 15] : s0;
        float g0  = __half2float(hw[s0  * 64 + lane]);
        float g1  = __half2float(hw[s1  * 64 + lane]);
        float g2  = __half2float(hw[s2  * 64 + lane]);
        float g3  = __half2float(hw[s3  * 64 + lane]);
        float g4  = __half2float(hw[s4  * 64 + lane]);
        float g5  = __half2float(hw[s5  * 64 + lane]);
        float g6  = __half2float(hw[s6  * 64 + lane]);
        float g7  = __half2float(hw[s7  * 64 + lane]);
        float g8  = __half2float(hw[s8  * 64 + lane]);
        float g9  = __half2float(hw[s9  * 64 + lane]);
        float g10 = __half2float(hw[s10 * 64 + lane]);
        float g11 = __half2float(hw[s11 * 64 + lane]);
        float g12 = __half2float(hw[s12 * 64 + lane]);
        float g13 = __half2float(hw[s13 * 64 + lane]);
        float g14 = __half2float(hw[s14 * 64 + lane]);
        float g15 = __half2float(hw[s15 * 64 + lane]);
        int inv = 16 - rem;
        if (inv < 0) inv = 0;                  // # clamped slots (SGPR)
        acc0 += g0;  acc1 += g1;  acc2 += g2;  acc3 += g3;
        acc0 += g4;  acc1 += g5;  acc2 += g6;  acc3 += g7;
        acc0 += g8;  acc1 += g9;  acc2 += g10; acc3 += g11;
        acc0 += g12; acc1 += g13; acc2 += g14; acc3 += g15;
        acc3 = fmaf(-(float)inv, g0, acc3);    // remove clamped duplicates
    }
    // h2 row value for (d, lane), unrounded f32 (closer to ref than fp16)
    float v = fmaxf(b1[lane] + dd * (((acc0 + acc1) + (acc2 + acc3)) + hself), 0.0f);
    h2row[wave][lane] = v;                     // wave-private: no barrier
    // hw2[d][j] = dd * sum_k h2[k]*W2[k][j]; halves split the k-range.
    int j = lane & 31;
    int half = lane >> 5;
    float sum = 0.0f;
#pragma unroll
    for (int k = 0; k < 32; ++k) {
        int kk = half * 32 + k;
        sum += h2row[wave][kk] * W2[kk * 32 + j];    // L1-hot broadcast line
    }
    sum += __shfl_xor(sum, 32, 64);            // combine k-halves
    if (half == 0)
        hw2out[d * 32 + j] = __float2half_rn(sum * dd);
}

// ---------------- layer-2 gather (R18 masked 16-deep) + z + linkpred dots --
__global__ __launch_bounds__(256) void k_gather2(const int* __restrict__ off,
                                                 const int* __restrict__ csr,
                                                 const float* __restrict__ dinv,
                                                 const __half* __restrict__ hw,
                                                 const float* __restrict__ b2,
                                                 const float* __restrict__ Wl,
                                                 float* __restrict__ outz,
                                                 float* __restrict__ uu,
                                                 float* __restrict__ vv) {
    int lane = threadIdx.x & 63;
    int half = lane >> 5;
    int j = lane & 31;
    int wave = threadIdx.x >> 6;
    int d = blockIdx.x * 4 + wave;             // grid = NN/4 exactly
    int start = (d == 0) ? 0 : off[d - 1];
    int end = off[d];
    start = __builtin_amdgcn_readfirstlane(start);
    end   = __builtin_amdgcn_readfirstlane(end);
    float dd = dinv[d];
    float hself = __half2float(hw[d * 32 + j]);      // hoisted
    float accA = 0.0f, accB = 0.0f, accC = 0.0f, accD = 0.0f;
    for (int e = start; e < end; e += 16) {
        int rem = end - e;                     // >= 1 (SGPR)
        int s0 = csr[e];                       // clamp target (uniform)
        int i1 = e + half;
        int sA = (half      < rem) ? csr[i1]      : s0;
        int sB = (half + 2  < rem) ? csr[i1 + 2]  : s0;
        int sC = (half + 4  < rem) ? csr[i1 + 4]  : s0;
        int sD = (half + 6  < rem) ? csr[i1 + 6]  : s0;
        int sE = (half + 8  < rem) ? csr[i1 + 8]  : s0;
        int sF = (half + 10 < rem) ? csr[i1 + 10] : s0;
        int sG = (half + 12 < rem) ? csr[i1 + 12] : s0;
        int sH = (half + 14 < rem) ? csr[i1 + 14] : s0;
        float gA = __half2float(hw[sA * 32 + j]);
        float gB = __half2float(hw[sB * 32 + j]);
        float gC = __half2float(hw[sC * 32 + j]);
        float gD = __half2float(hw[sD * 32 + j]);
        float gE = __half2float(hw[sE * 32 + j]);
        float gF = __half2float(hw[sF * 32 + j]);
        float gG = __half2float(hw[sG * 32 + j]);
        float gH = __half2float(hw[sH * 32 + j]);
        int nv = (rem - half + 1) >> 1;        // valid slots this half
        if (nv > 8) nv = 8;
        int inv = 8 - nv;                      // clamped slots this half
        accA += gA; accB += gB; accC += gC; accD += gD;
        accA += gE; accB += gF; accC += gG; accD += gH;
        accD = fmaf(-(float)inv, gH, accD);    // gH == r0 whenever inv > 0
    }
    float acc = (accA + accB) + (accC + accD);
    acc += __shfl(acc, lane ^ 32, 64);         // combine halves (full exec)
    float z = b2[j] + dd * (acc + hself);      // valid on all lanes
    if (half == 0)
        outz[d * 32 + j] = z;
    // per-node link-pred dots (all lanes; halves compute identical values)
    float p0 = z * Wl[j];
    float p1 = z * Wl[32 + j];
    p0 += __shfl_xor(p0, 1, 64);  p1 += __shfl_xor(p1, 1, 64);
    p0 += __shfl_xor(p0, 2, 64);  p1 += __shfl_xor(p1, 2, 64);
    p0 += __shfl_xor(p0, 4, 64);  p1 += __shfl_xor(p1, 4, 64);
    p0 += __shfl_xor(p0, 8, 64);  p1 += __shfl_xor(p1, 8, 64);
    p0 += __shfl_xor(p0, 16, 64); p1 += __shfl_xor(p1, 16, 64);
    if (lane == 0) { uu[d] = p0; vv[d] = p1; }
}

// ---------------- link prediction head: pred = u[s] + v[d] + bl ------------
__global__ __launch_bounds__(256) void k_linkpred(const int* __restrict__ sidx,
                                                  const int* __restrict__ didx,
                                                  const float* __restrict__ uu,
                                                  const float* __restrict__ vv,
                                                  const float* __restrict__ bl,
                                                  float* __restrict__ pred) {
    int e = blockIdx.x * 256 + threadIdx.x;
    if (e < NEL)
        pred[e] = uu[sidx[e]] + vv[didx[e]] + bl[0];
}

extern "C" void kernel_launch(void* const* d_in, const int* in_sizes, int n_in,
                              void* d_out, int out_size, void* d_ws, size_t ws_size,
                              hipStream_t stream) {
    const float* x    = (const float*)d_in[0];
    const float* pos  = (const float*)d_in[1];
    const float* W1   = (const float*)d_in[2];
    const float* b1   = (const float*)d_in[3];
    const float* W2   = (const float*)d_in[4];
    const float* b2   = (const float*)d_in[5];
    const float* Wl   = (const float*)d_in[6];
    const float* bl   = (const float*)d_in[7];
    const int*   ei   = (const int*)d_in[8];   // [2, NE]
    const int*   eli  = (const int*)d_in[9];   // [2, NEL]
    const int* src  = ei;
    const int* dst  = ei + NE;
    const int* lsrc = eli;
    const int* ldst = eli + NEL;

    float* out_z    = (float*)d_out;            // [NN, 32]
    float* out_pred = (float*)d_out + NN * 32;  // [NEL]

    // workspace: dinv[NN]f | off[NN]i | csr[NE]i | hw1'[NN*64]h + hw2'[NN*32]h
    //            (part[196*196*96]i = 14.75 MB aliases hw1+hw2 span = 19.2 MB,
    //            dead after k_build; csr followed by hw1 gives the <=15-int
    //            over-read slack) | uu[NN]f | vv[NN]f | rcnt[196*196]i ~= 28 MB
    float*  dinv  = (float*)d_ws;
    int*    off   = (int*)(dinv + NN);
    int*    csr   = off + NN;
    __half* hw1   = (__half*)(csr + NE);
    int*    part  = (int*)hw1;                  // 14.75 MB <= 19.2 MB span
    __half* hw2   = hw1 + NN * 64;
    float*  uu    = (float*)(hw2 + NN * 32);
    float*  vv    = uu + NN;
    int*    rcnt  = (int*)(vv + NN);            // 154 KB

    // 1) deterministic partition (no memset, no global atomics)
    k_part<<<(NE + TPE - 1) / TPE, 256, 0, stream>>>(src, dst, part, rcnt);

    // 2) per-bucket LDS sort (totals from rcnt, prefix fused, +dinv)
    k_build<<<NBUCK, 256, 0, stream>>>(rcnt, part, csr, off, dinv);

    // 3) hw1' = dinv * ([x|pos] @ W1), MFMA bf16-split (part now dead)
    k_hw1<<<(NN + TM - 1) / TM, 256, 0, stream>>>(x, pos, W1, dinv, hw1);

    // 4) layer-1 gather + relu + FUSED hw2 row-GEMM -> hw2 (fp16)
    k_gather1<<<NN / 4, 256, 0, stream>>>(off, csr, dinv, hw1, b1, W2, hw2);

    // 5) layer-2 gather + bias -> z (fp32 out) + per-node linkpred dots u,v
    k_gather2<<<NN / 4, 256, 0, stream>>>(off, csr, dinv, hw2, b2, Wl,
                                          out_z, uu, vv);

    // 6) link prediction: pred = u[s] + v[d] + bl
    k_linkpred<<<(NEL + 255) / 256, 256, 0, stream>>>(lsrc, ldst, uu, vv, bl,
                                                      out_pred);
}

// Round 13
// 265.669 us; speedup vs baseline: 1.1039x; 1.1039x over previous
//
#include <hip/hip_runtime.h>
#include <hip/hip_fp16.h>

#define NN 100000     // num nodes
#define NE 1600000    // num edges
#define NEL 200000    // link-pred edges
#define TM 64         // nodes per block in k_hw1

// Bucketed CSR build (R12-config, atomic+packed — best of 5 measured designs):
// bucket = dst >> 9. Alternatives ALL measured worse: fused part+build (+19,
// R9), atomic-append scatter (17x write amp +151, R10), deterministic
// block-private runs (+21, R12 — latency-bound k_build needs packed reads),
// bucket-direct gather (4.8x, R7), megakernel (4.4x, R6). Do not revisit.
#define NBUCK 196     // ceil(NN/512)
#define CAPB  10240   // per-bucket capacity (mean 8163, sigma ~90)
#define TPE   8192    // edges per k_part block (196 blocks)
#define EPT   32      // edges per thread (TPE/256), register-staged

typedef short s16x8 __attribute__((ext_vector_type(8)));
typedef float f32x4 __attribute__((ext_vector_type(4)));

__device__ __forceinline__ unsigned short bf16hi(float v) {
    unsigned u = __float_as_uint(v);
    return (unsigned short)((u + 0x7FFFu + ((u >> 16) & 1u)) >> 16);
}
__device__ __forceinline__ float bf16tof(unsigned short b) {
    return __uint_as_float(((unsigned)b) << 16);
}

// ---------------- CSR build, pass A: partition edges into buckets ----------
// R27: register-staged (one dst+src read instead of dst twice + src once;
// R5-proven pattern at EPT=8, scaled). 196 blocks are latency-bound, so
// each removed dependent global read pays off directly.
__global__ __launch_bounds__(256) void k_part(const int* __restrict__ src,
                                              const int* __restrict__ dst,
                                              int* __restrict__ gcur,
                                              int* __restrict__ part) {
    __shared__ int hist[NBUCK];
    __shared__ int base[NBUCK];
    __shared__ int rk[NBUCK];
    int tid = threadIdx.x;
    for (int i = tid; i < NBUCK; i += 256) { hist[i] = 0; rk[i] = 0; }
    __syncthreads();
    int e0 = blockIdx.x * TPE;
    int d[EPT], s[EPT];
#pragma unroll
    for (int k = 0; k < EPT; ++k) {
        int e = e0 + tid + k * 256;
        bool ok = e < NE;
        d[k] = ok ? dst[e] : -1;
        s[k] = ok ? src[e] : 0;
    }
#pragma unroll
    for (int k = 0; k < EPT; ++k)
        if (d[k] >= 0) atomicAdd(&hist[d[k] >> 9], 1);
    __syncthreads();
    for (int i = tid; i < NBUCK; i += 256)
        base[i] = i * CAPB + atomicAdd(&gcur[i], hist[i]);
    __syncthreads();
#pragma unroll
    for (int k = 0; k < EPT; ++k)
        if (d[k] >= 0) {
            int b = d[k] >> 9;
            int r = atomicAdd(&rk[b], 1);
            part[base[b] + r] = ((d[k] & 511) << 17) | s[k];   // src < 2^17
        }
}

// ---------------- CSR build, pass B: per-bucket LDS sort (prefix fused) ----
__global__ __launch_bounds__(256) void k_build(const int* __restrict__ gcur,
                                               const int* __restrict__ part,
                                               int* __restrict__ csr,
                                               int* __restrict__ off,
                                               float* __restrict__ dinv) {
    __shared__ int cnts[256];
    __shared__ int hist[512];
    __shared__ int loff[512];
    __shared__ int ssum[256];
    __shared__ int csrbuf[CAPB];
    int b = blockIdx.x;
    int tid = threadIdx.x;
    cnts[tid] = (tid < NBUCK) ? gcur[tid] : 0;       // inline bucket prefix
    __syncthreads();
    for (int st = 1; st < 256; st <<= 1) {
        int tmp = (tid >= st) ? cnts[tid - st] : 0;
        __syncthreads();
        cnts[tid] += tmp;
        __syncthreads();
    }
    int obase = (b == 0) ? 0 : cnts[b - 1];
    int cnt = gcur[b];
    int pbase = b * CAPB;
    hist[tid] = 0; hist[tid + 256] = 0;
    __syncthreads();
    for (int i = tid; i < cnt; i += 256)
        atomicAdd(&hist[part[pbase + i] >> 17], 1);
    __syncthreads();
    int a0 = hist[2 * tid], a1 = hist[2 * tid + 1];
    int pairs = a0 + a1;
    ssum[tid] = pairs;
    __syncthreads();
    for (int st = 1; st < 256; st <<= 1) {
        int tmp = (tid >= st) ? ssum[tid - st] : 0;
        __syncthreads();
        ssum[tid] += tmp;
        __syncthreads();
    }
    int pexcl = ssum[tid] - pairs;
    loff[2 * tid] = pexcl;
    loff[2 * tid + 1] = pexcl + a0;
    __syncthreads();
    for (int i = tid; i < 512; i += 256) {
        int d = b * 512 + i;
        if (d < NN) {
            int c = hist[i];
            off[d] = obase + loff[i] + c;            // end of row d
            dinv[d] = rsqrtf((float)(c + 1));        // +1 self-loop
        }
    }
    hist[tid] = 0; hist[tid + 256] = 0;              // reuse as rank counters
    __syncthreads();
    for (int i = tid; i < cnt; i += 256) {
        int rec = part[pbase + i];
        int dl = rec >> 17;
        int r = atomicAdd(&hist[dl], 1);
        csrbuf[loff[dl] + r] = rec & 0x1FFFF;
    }
    __syncthreads();
    for (int i = tid; i < cnt; i += 256)             // coalesced flush
        csr[obase + i] = csrbuf[i];
}

// ---------------- hw1' = dinv * ([x|pos] @ W1)  (80 -> 64), MFMA bf16-split
// bf16 hi/lo split (Ahi*Bhi + Ahi*Blo + Alo*Bhi) -> fp32-class accuracy.
#define HW1_K 104
__global__ __launch_bounds__(256) void k_hw1(const float* __restrict__ x,
                                             const float* __restrict__ pos,
                                             const float* __restrict__ W1,
                                             const float* __restrict__ dinv,
                                             __half* __restrict__ hw1) {
    __shared__ unsigned short ahi[64 * HW1_K];
    __shared__ unsigned short alo[64 * HW1_K];
    __shared__ unsigned short bhi[64 * HW1_K];
    __shared__ unsigned short blo[64 * HW1_K];
    __shared__ float sdin[64];
    int tid = threadIdx.x;
    int nb = blockIdx.x * 64;
    for (int i = tid; i < 64 * 24; i += 256) {
        int r = i / 24, c = i - r * 24;
        ahi[r * HW1_K + 80 + c] = 0; alo[r * HW1_K + 80 + c] = 0;
        bhi[r * HW1_K + 80 + c] = 0; blo[r * HW1_K + 80 + c] = 0;
    }
    for (int i = tid; i < 64 * 64; i += 256) {
        int r = i >> 6, c = i & 63;
        int g = nb + r;
        float v = (g < NN) ? x[g * 64 + c] : 0.0f;
        unsigned short h = bf16hi(v);
        ahi[r * HW1_K + c] = h;
        alo[r * HW1_K + c] = bf16hi(v - bf16tof(h));
    }
    for (int i = tid; i < 64 * 16; i += 256) {
        int r = i >> 4, c = i & 15;
        int g = nb + r;
        float v = (g < NN) ? pos[g * 16 + c] : 0.0f;
        unsigned short h = bf16hi(v);
        ahi[r * HW1_K + 64 + c] = h;
        alo[r * HW1_K + 64 + c] = bf16hi(v - bf16tof(h));
    }
    for (int i = tid; i < 80 * 64; i += 256) {
        int k = i >> 6, c = i & 63;
        float v = W1[i];
        unsigned short h = bf16hi(v);
        bhi[c * HW1_K + k] = h;
        blo[c * HW1_K + k] = bf16hi(v - bf16tof(h));
    }
    for (int i = tid; i < 64; i += 256) {
        int g = nb + i;
        sdin[i] = (g < NN) ? dinv[g] : 0.0f;
    }
    __syncthreads();
    int wave = tid >> 6, lane = tid & 63;
    int frow = lane & 15, fq = lane >> 4;
    int r0 = wave * 16;                        // wave owns 16 rows x 64 cols
    int aoff = (r0 + frow) * HW1_K + fq * 8;
    s16x8 ah0 = *(s16x8*)&ahi[aoff];
    s16x8 ah1 = *(s16x8*)&ahi[aoff + 32];
    s16x8 ah2 = *(s16x8*)&ahi[aoff + 64];
    s16x8 al0 = *(s16x8*)&alo[aoff];
    s16x8 al1 = *(s16x8*)&alo[aoff + 32];
    s16x8 al2 = *(s16x8*)&alo[aoff + 64];
    f32x4 acc[4];
#pragma unroll
    for (int ct = 0; ct < 4; ++ct) {
        acc[ct] = (f32x4)(0.0f);
        int boff = (ct * 16 + frow) * HW1_K + fq * 8;
        s16x8 bh0 = *(s16x8*)&bhi[boff];
        s16x8 bh1 = *(s16x8*)&bhi[boff + 32];
        s16x8 bh2 = *(s16x8*)&bhi[boff + 64];
        s16x8 bl0 = *(s16x8*)&blo[boff];
        s16x8 bl1 = *(s16x8*)&blo[boff + 32];
        s16x8 bl2 = *(s16x8*)&blo[boff + 64];
        acc[ct] = __builtin_amdgcn_mfma_f32_16x16x32_bf16(ah0, bh0, acc[ct], 0, 0, 0);
        acc[ct] = __builtin_amdgcn_mfma_f32_16x16x32_bf16(ah1, bh1, acc[ct], 0, 0, 0);
        acc[ct] = __builtin_amdgcn_mfma_f32_16x16x32_bf16(ah2, bh2, acc[ct], 0, 0, 0);
        acc[ct] = __builtin_amdgcn_mfma_f32_16x16x32_bf16(ah0, bl0, acc[ct], 0, 0, 0);
        acc[ct] = __builtin_amdgcn_mfma_f32_16x16x32_bf16(ah1, bl1, acc[ct], 0, 0, 0);
        acc[ct] = __builtin_amdgcn_mfma_f32_16x16x32_bf16(ah2, bl2, acc[ct], 0, 0, 0);
        acc[ct] = __builtin_amdgcn_mfma_f32_16x16x32_bf16(al0, bh0, acc[ct], 0, 0, 0);
        acc[ct] = __builtin_amdgcn_mfma_f32_16x16x32_bf16(al1, bh1, acc[ct], 0, 0, 0);
        acc[ct] = __builtin_amdgcn_mfma_f32_16x16x32_bf16(al2, bh2, acc[ct], 0, 0, 0);
    }
#pragma unroll
    for (int ct = 0; ct < 4; ++ct) {
        int col = ct * 16 + frow;
#pragma unroll
        for (int i = 0; i < 4; ++i) {
            int r = r0 + fq * 4 + i;           // C/D: col=lane&15, row=(lane>>4)*4+i
            int g = nb + r;
            if (g < NN)
                hw1[g * 64 + col] = __float2half_rn(acc[ct][i] * sdin[r]);
        }
    }
}

// ---------------- layer-1 gather + FUSED hw2 row-GEMM (slim epilogue) ------
// Gather loop = proven R18 masked 16-deep (chip random-line ceiling ~30
// req/ns; R12 showed dur is request-limited, not byte-limited — FETCH
// halved, time unchanged. Do not restructure). Fused hw2 (R8, −21 us);
// slim W2-direct epilogue (R11, −6 us). Landmines: R15 channel-slice 3.2x;
// R16 index arrays 5x; R6 mega 4.4x; R7 bucket-scatter 4.8x; R10 17x amp.
__global__ __launch_bounds__(256) void k_gather1(const int* __restrict__ off,
                                                 const int* __restrict__ csr,
                                                 const float* __restrict__ dinv,
                                                 const __half* __restrict__ hw,
                                                 const float* __restrict__ b1,
                                                 const float* __restrict__ W2,
                                                 __half* __restrict__ hw2out) {
    __shared__ float h2row[4][64];             // 1 KB, wave-private rows
    int tid = threadIdx.x;
    int lane = tid & 63;
    int wave = tid >> 6;
    int d = blockIdx.x * 4 + wave;             // grid = NN/4 exactly
    int start = (d == 0) ? 0 : off[d - 1];
    int end = off[d];
    start = __builtin_amdgcn_readfirstlane(start);   // SGPR bounds ->
    end   = __builtin_amdgcn_readfirstlane(end);     // scalar csr loads
    float dd = dinv[d];
    float hself = __half2float(hw[d * 64 + lane]);   // hoisted
    float acc0 = 0.0f, acc1 = 0.0f, acc2 = 0.0f, acc3 = 0.0f;
    for (int e = start; e < end; e += 16) {
        int rem = end - e;                     // >= 1 (SGPR)
        int s0 = csr[e];
        int s1  = (rem > 1)  ? csr[e + 1]  : s0;
        int s2  = (rem > 2)  ? csr[e + 2]  : s0;
        int s3  = (rem > 3)  ? csr[e + 3]  : s0;
        int s4  = (rem > 4)  ? csr[e + 4]  : s0;
        int s5  = (rem > 5)  ? csr[e + 5]  : s0;
        int s6  = (rem > 6)  ? csr[e + 6]  : s0;
        int s7  = (rem > 7)  ? csr[e + 7]  : s0;
        int s8  = (rem > 8)  ? csr[e + 8]  : s0;
        int s9  = (rem > 9)  ? csr[e + 9]  : s0;
        int s10 = (rem > 10) ? csr[e + 10] : s0;
        int s11 = (rem > 11) ? csr[e + 11] : s0;
        int s12 = (rem > 12) ? csr[e + 12] : s0;
        int s13 = (rem > 13) ? csr[e + 13] : s0;
        int s14 = (rem > 14) ? csr[e + 14] : s0;
        int s15 = (rem > 15) ? csr[e + 15] : s0;
        float g0  = __half2float(hw[s0  * 64 + lane]);
        float g1  = __half2float(hw[s1  * 64 + lane]);
        float g2  = __half2float(hw[s2  * 64 + lane]);
        float g3  = __half2float(hw[s3  * 64 + lane]);
        float g4  = __half2float(hw[s4  * 64 + lane]);
        float g5  = __half2float(hw[s5  * 64 + lane]);
        float g6  = __half2float(hw[s6  * 64 + lane]);
        float g7  = __half2float(hw[s7  * 64 + lane]);
        float g8  = __half2float(hw[s8  * 64 + lane]);
        float g9  = __half2float(hw[s9  * 64 + lane]);
        float g10 = __half2float(hw[s10 * 64 + lane]);
        float g11 = __half2float(hw[s11 * 64 + lane]);
        float g12 = __half2float(hw[s12 * 64 + lane]);
        float g13 = __half2float(hw[s13 * 64 + lane]);
        float g14 = __half2float(hw[s14 * 64 + lane]);
        float g15 = __half2float(hw[s15 * 64 + lane]);
        int inv = 16 - rem;
        if (inv < 0) inv = 0;                  // # clamped slots (SGPR)
        acc0 += g0;  acc1 += g1;  acc2 += g2;  acc3 += g3;
        acc0 += g4;  acc1 += g5;  acc2 += g6;  acc3 += g7;
        acc0 += g8;  acc1 += g9;  acc2 += g10; acc3 += g11;
        acc0 += g12; acc1 += g13; acc2 += g14; acc3 += g15;
        acc3 = fmaf(-(float)inv, g0, acc3);    // remove clamped duplicates
    }
    // h2 row value for (d, lane), unrounded f32 (closer to ref than fp16)
    float v = fmaxf(b1[lane] + dd * (((acc0 + acc1) + (acc2 + acc3)) + hself), 0.0f);
    h2row[wave][lane] = v;                     // wave-private: no barrier
    // hw2[d][j] = dd * sum_k h2[k]*W2[k][j]; halves split the k-range.
    int j = lane & 31;
    int half = lane >> 5;
    float sum = 0.0f;
#pragma unroll
    for (int k = 0; k < 32; ++k) {
        int kk = half * 32 + k;
        sum += h2row[wave][kk] * W2[kk * 32 + j];    // L1-hot broadcast line
    }
    sum += __shfl_xor(sum, 32, 64);            // combine k-halves
    if (half == 0)
        hw2out[d * 32 + j] = __float2half_rn(sum * dd);
}

// ---------------- layer-2 gather (R18 masked 16-deep) + z + linkpred dots --
__global__ __launch_bounds__(256) void k_gather2(const int* __restrict__ off,
                                                 const int* __restrict__ csr,
                                                 const float* __restrict__ dinv,
                                                 const __half* __restrict__ hw,
                                                 const float* __restrict__ b2,
                                                 const float* __restrict__ Wl,
                                                 float* __restrict__ outz,
                                                 float* __restrict__ uu,
                                                 float* __restrict__ vv) {
    int lane = threadIdx.x & 63;
    int half = lane >> 5;
    int j = lane & 31;
    int wave = threadIdx.x >> 6;
    int d = blockIdx.x * 4 + wave;             // grid = NN/4 exactly
    int start = (d == 0) ? 0 : off[d - 1];
    int end = off[d];
    start = __builtin_amdgcn_readfirstlane(start);
    end   = __builtin_amdgcn_readfirstlane(end);
    float dd = dinv[d];
    float hself = __half2float(hw[d * 32 + j]);      // hoisted
    float accA = 0.0f, accB = 0.0f, accC = 0.0f, accD = 0.0f;
    for (int e = start; e < end; e += 16) {
        int rem = end - e;                     // >= 1 (SGPR)
        int s0 = csr[e];                       // clamp target (uniform)
        int i1 = e + half;
        int sA = (half      < rem) ? csr[i1]      : s0;
        int sB = (half + 2  < rem) ? csr[i1 + 2]  : s0;
        int sC = (half + 4  < rem) ? csr[i1 + 4]  : s0;
        int sD = (half + 6  < rem) ? csr[i1 + 6]  : s0;
        int sE = (half + 8  < rem) ? csr[i1 + 8]  : s0;
        int sF = (half + 10 < rem) ? csr[i1 + 10] : s0;
        int sG = (half + 12 < rem) ? csr[i1 + 12] : s0;
        int sH = (half + 14 < rem) ? csr[i1 + 14] : s0;
        float gA = __half2float(hw[sA * 32 + j]);
        float gB = __half2float(hw[sB * 32 + j]);
        float gC = __half2float(hw[sC * 32 + j]);
        float gD = __half2float(hw[sD * 32 + j]);
        float gE = __half2float(hw[sE * 32 + j]);
        float gF = __half2float(hw[sF * 32 + j]);
        float gG = __half2float(hw[sG * 32 + j]);
        float gH = __half2float(hw[sH * 32 + j]);
        int nv = (rem - half + 1) >> 1;        // valid slots this half
        if (nv > 8) nv = 8;
        int inv = 8 - nv;                      // clamped slots this half
        accA += gA; accB += gB; accC += gC; accD += gD;
        accA += gE; accB += gF; accC += gG; accD += gH;
        accD = fmaf(-(float)inv, gH, accD);    // gH == r0 whenever inv > 0
    }
    float acc = (accA + accB) + (accC + accD);
    acc += __shfl(acc, lane ^ 32, 64);         // combine halves (full exec)
    float z = b2[j] + dd * (acc + hself);      // valid on all lanes
    if (half == 0)
        outz[d * 32 + j] = z;
    // per-node link-pred dots (all lanes; halves compute identical values)
    float p0 = z * Wl[j];
    float p1 = z * Wl[32 + j];
    p0 += __shfl_xor(p0, 1, 64);  p1 += __shfl_xor(p1, 1, 64);
    p0 += __shfl_xor(p0, 2, 64);  p1 += __shfl_xor(p1, 2, 64);
    p0 += __shfl_xor(p0, 4, 64);  p1 += __shfl_xor(p1, 4, 64);
    p0 += __shfl_xor(p0, 8, 64);  p1 += __shfl_xor(p1, 8, 64);
    p0 += __shfl_xor(p0, 16, 64); p1 += __shfl_xor(p1, 16, 64);
    if (lane == 0) { uu[d] = p0; vv[d] = p1; }
}

// ---------------- link prediction head: pred = u[s] + v[d] + bl ------------
// x4 vectorized edge-index loads + float4 store; uu/vv lookups are 4B
// random reads into 800 KB L2-resident tables.
__global__ __launch_bounds__(256) void k_linkpred(const int* __restrict__ sidx,
                                                  const int* __restrict__ didx,
                                                  const float* __restrict__ uu,
                                                  const float* __restrict__ vv,
                                                  const float* __restrict__ bl,
                                                  float* __restrict__ pred) {
    int e4 = (blockIdx.x * 256 + threadIdx.x) * 4;
    if (e4 < NEL) {                            // NEL % 4 == 0
        int4 s = *(const int4*)&sidx[e4];
        int4 d = *(const int4*)&didx[e4];
        float b = bl[0];
        float4 p;
        p.x = uu[s.x] + vv[d.x] + b;
        p.y = uu[s.y] + vv[d.y] + b;
        p.z = uu[s.z] + vv[d.z] + b;
        p.w = uu[s.w] + vv[d.w] + b;
        *(float4*)&pred[e4] = p;
    }
}

extern "C" void kernel_launch(void* const* d_in, const int* in_sizes, int n_in,
                              void* d_out, int out_size, void* d_ws, size_t ws_size,
                              hipStream_t stream) {
    const float* x    = (const float*)d_in[0];
    const float* pos  = (const float*)d_in[1];
    const float* W1   = (const float*)d_in[2];
    const float* b1   = (const float*)d_in[3];
    const float* W2   = (const float*)d_in[4];
    const float* b2   = (const float*)d_in[5];
    const float* Wl   = (const float*)d_in[6];
    const float* bl   = (const float*)d_in[7];
    const int*   ei   = (const int*)d_in[8];   // [2, NE]
    const int*   eli  = (const int*)d_in[9];   // [2, NEL]
    const int* src  = ei;
    const int* dst  = ei + NE;
    const int* lsrc = eli;
    const int* ldst = eli + NEL;

    float* out_z    = (float*)d_out;            // [NN, 32]
    float* out_pred = (float*)d_out + NN * 32;  // [NEL]

    // workspace: dinv[NN]f | off[NN]i | gcur[NBUCK] | csr[NE]i |
    //            hw1'[NN*64]h (aliases part[NBUCK*CAPB]i = 8.0 MB, dead after
    //            k_build; also slack for the <=15-int csr over-reads) |
    //            hw2'[NN*32]h | uu[NN]f | vv[NN]f    ~= 28 MB
    float*  dinv  = (float*)d_ws;
    int*    off   = (int*)(dinv + NN);
    int*    gcur  = off + NN;
    int*    csr   = gcur + NBUCK;
    __half* hw1   = (__half*)(csr + NE);
    int*    part  = (int*)hw1;                  // 8.0 MB <= hw1's 12.8 MB
    __half* hw2   = hw1 + NN * 64;
    float*  uu    = (float*)(hw2 + NN * 32);
    float*  vv    = uu + NN;

    // 1) CSR build: partition -> per-bucket LDS sort (prefix fused, +dinv)
    hipMemsetAsync(gcur, 0, NBUCK * sizeof(int), stream);
    k_part<<<(NE + TPE - 1) / TPE, 256, 0, stream>>>(src, dst, gcur, part);
    k_build<<<NBUCK, 256, 0, stream>>>(gcur, part, csr, off, dinv);

    // 2) hw1' = dinv * ([x|pos] @ W1), MFMA bf16-split (part now dead)
    k_hw1<<<(NN + TM - 1) / TM, 256, 0, stream>>>(x, pos, W1, dinv, hw1);

    // 3) layer-1 gather + relu + FUSED hw2 row-GEMM -> hw2 (fp16)
    k_gather1<<<NN / 4, 256, 0, stream>>>(off, csr, dinv, hw1, b1, W2, hw2);

    // 4) layer-2 gather + bias -> z (fp32 out) + per-node linkpred dots u,v
    k_gather2<<<NN / 4, 256, 0, stream>>>(off, csr, dinv, hw2, b2, Wl,
                                          out_z, uu, vv);

    // 5) link prediction: pred = u[s] + v[d] + bl
    k_linkpred<<<(NEL / 4 + 255) / 256, 256, 0, stream>>>(lsrc, ldst, uu, vv,
                                                          bl, out_pred);
}